// Round 1
// baseline (3114.943 us; speedup 1.0000x reference)
//
#include <hip/hip_runtime.h>

#define IN_F 4096
#define OUT_F 11008
#define BM 128
#define BN 128
#define BK 64

typedef __attribute__((ext_vector_type(8))) short bf16x8;   // 8 bf16 (4 VGPR) MFMA operand
typedef __attribute__((ext_vector_type(4))) float f32x4;
typedef __attribute__((ext_vector_type(4))) unsigned short us4;
typedef __attribute__((ext_vector_type(8))) unsigned short us8;

__device__ __forceinline__ unsigned short f2bf(float f) {
  unsigned int u = __float_as_uint(f);
  u += 0x7FFFu + ((u >> 16) & 1u);   // RNE
  return (unsigned short)(u >> 16);
}

__global__ __launch_bounds__(256, 2) void nf4_gemm(
    const float* __restrict__ X, const int* __restrict__ Wp,
    const float* __restrict__ Amax, const float* __restrict__ Bias,
    float* __restrict__ Out, int M) {
  __shared__ unsigned short As[BM * BK];   // 16 KiB, XOR-swizzled
  __shared__ unsigned short Bs[BN * BK];   // 16 KiB, XOR-swizzled
  __shared__ float lutS[16];

  const int t = threadIdx.x;
  const int l = t & 63;
  const int wid = t >> 6;

  if (t < 16) {
    const float lut[16] = {-1.0f, -0.6961928009986877f, -0.5250730514526367f,
        -0.39491719007492065f, -0.28444138169288635f, -0.18477343022823334f,
        -0.08820830285549164f, 0.0f, 0.07107656449079514f, 0.14263366162776947f,
        0.22430233657360077f, 0.3203405737876892f, 0.4407068192958832f,
        0.5905631184577942f, 0.796090841293335f, 1.0f};
    lutS[t] = lut[t];
  }

  const int ntile = OUT_F / BN;              // 86
  const int m0 = (blockIdx.x / ntile) * BM;
  const int n0 = (blockIdx.x % ntile) * BN;

  // staging coords
  const int ar = t >> 4;     // A: row-within-pass (16 rows/pass, 8 passes)
  const int ac4 = t & 15;    // A: which float4 in the 64-wide k strip
  const int br = t >> 3;     // B: row-within-pass (32 rows/pass, 4 passes)
  const int bg = t & 7;      // B: which int4 (4 packed int32 = 8 weights)

  // wave 64x64 sub-tile
  const int wm = (wid >> 1) * 64;
  const int wn = (wid & 1) * 64;

  f32x4 acc[4][4];
#pragma unroll
  for (int i = 0; i < 4; ++i)
#pragma unroll
    for (int j = 0; j < 4; ++j) acc[i][j] = {0.f, 0.f, 0.f, 0.f};

  __syncthreads();   // lutS visible

  for (int k0 = 0; k0 < IN_F; k0 += BK) {
    // ---- stage A: 128x64 fp32 -> bf16 (swizzled LDS) ----
#pragma unroll
    for (int p = 0; p < 8; ++p) {
      const int r = p * 16 + ar;
      const float4 v = *reinterpret_cast<const float4*>(
          X + (size_t)(m0 + r) * IN_F + k0 + ac4 * 4);
      us4 h;
      h[0] = f2bf(v.x); h[1] = f2bf(v.y); h[2] = f2bf(v.z); h[3] = f2bf(v.w);
      const int byte = r * 128 + ((ac4 * 8) ^ ((r & 7) << 4));
      *reinterpret_cast<us4*>(reinterpret_cast<char*>(As) + byte) = h;
    }
    // ---- stage B: dequant 128x32 packed int32 -> 128x64 bf16 (swizzled LDS) ----
#pragma unroll
    for (int p = 0; p < 4; ++p) {
      const int r = p * 32 + br;
      const float amv = Amax[(size_t)(n0 + r) * (IN_F / 64) + (k0 >> 6)];
      const int4 pk = *reinterpret_cast<const int4*>(
          Wp + (size_t)(n0 + r) * (IN_F / 2) + (k0 >> 1) + bg * 4);
      us8 h;
      {
        int c;
        c = pk.x & 255; h[0] = f2bf(lutS[c & 15] * amv); h[1] = f2bf(lutS[c >> 4] * amv);
        c = pk.y & 255; h[2] = f2bf(lutS[c & 15] * amv); h[3] = f2bf(lutS[c >> 4] * amv);
        c = pk.z & 255; h[4] = f2bf(lutS[c & 15] * amv); h[5] = f2bf(lutS[c >> 4] * amv);
        c = pk.w & 255; h[6] = f2bf(lutS[c & 15] * amv); h[7] = f2bf(lutS[c >> 4] * amv);
      }
      const int byte = r * 128 + ((bg * 16) ^ ((r & 7) << 4));
      *reinterpret_cast<us8*>(reinterpret_cast<char*>(Bs) + byte) = h;
    }
    __syncthreads();

    // ---- MFMA over the 64-wide k tile ----
#pragma unroll
    for (int kk = 0; kk < BK; kk += 32) {
      bf16x8 af[4], bfv[4];
      const int kb = (kk + ((l >> 4) << 3)) * 2;   // byte col within 128B row (mult of 16)
#pragma unroll
      for (int i = 0; i < 4; ++i) {
        const int row = wm + i * 16 + (l & 15);
        af[i] = *reinterpret_cast<const bf16x8*>(
            reinterpret_cast<const char*>(As) + row * 128 + (kb ^ ((row & 7) << 4)));
      }
#pragma unroll
      for (int j = 0; j < 4; ++j) {
        const int row = wn + j * 16 + (l & 15);
        bfv[j] = *reinterpret_cast<const bf16x8*>(
            reinterpret_cast<const char*>(Bs) + row * 128 + (kb ^ ((row & 7) << 4)));
      }
#pragma unroll
      for (int i = 0; i < 4; ++i)
#pragma unroll
        for (int j = 0; j < 4; ++j)
          acc[i][j] = __builtin_amdgcn_mfma_f32_16x16x32_bf16(af[i], bfv[j], acc[i][j], 0, 0, 0);
    }
    __syncthreads();
  }

  // ---- epilogue: C = acc + bias ----
  const int crow0 = m0 + wm + ((l >> 4) << 2);
  const int ccol0 = n0 + wn + (l & 15);
#pragma unroll
  for (int j = 0; j < 4; ++j) {
    const float bv = Bias[ccol0 + j * 16];
#pragma unroll
    for (int i = 0; i < 4; ++i) {
#pragma unroll
      for (int rg = 0; rg < 4; ++rg) {
        const int row = crow0 + i * 16 + rg;
        Out[(size_t)row * OUT_F + ccol0 + j * 16] = acc[i][j][rg] + bv;
      }
    }
  }
}

extern "C" void kernel_launch(void* const* d_in, const int* in_sizes, int n_in,
                              void* d_out, int out_size, void* d_ws, size_t ws_size,
                              hipStream_t stream) {
  const float* X = (const float*)d_in[0];
  const int* Wp = (const int*)d_in[1];
  const float* Amax = (const float*)d_in[2];
  const float* Bias = (const float*)d_in[3];
  float* Out = (float*)d_out;

  const int M = in_sizes[0] / IN_F;          // 8192
  const int grid = (M / BM) * (OUT_F / BN);  // 64 * 86 = 5504
  nf4_gemm<<<grid, 256, 0, stream>>>(X, Wp, Amax, Bias, Out, M);
}

// Round 2
// 970.628 us; speedup vs baseline: 3.2092x; 3.2092x over previous
//
#include <hip/hip_runtime.h>

#define IN_F 4096
#define OUT_F 11008
#define BM 128
#define BN 128
#define BK 64

typedef __attribute__((ext_vector_type(8))) short bf16x8;   // 8 bf16 (4 VGPR) MFMA operand
typedef __attribute__((ext_vector_type(4))) float f32x4;
typedef __attribute__((ext_vector_type(4))) unsigned short us4;
typedef __attribute__((ext_vector_type(8))) unsigned short us8;

__device__ __forceinline__ unsigned short f2bf(float f) {
  unsigned int u = __float_as_uint(f);
  u += 0x7FFFu + ((u >> 16) & 1u);   // RNE
  return (unsigned short)(u >> 16);
}

// ---------------- prepass 1: X fp32 -> bf16 ----------------
__global__ __launch_bounds__(256) void cvt_x(const float* __restrict__ X,
                                             unsigned short* __restrict__ Xb, int n8) {
  for (int i = blockIdx.x * blockDim.x + threadIdx.x; i < n8;
       i += gridDim.x * blockDim.x) {
    const float4 a = reinterpret_cast<const float4*>(X)[2 * i];
    const float4 b = reinterpret_cast<const float4*>(X)[2 * i + 1];
    us8 h;
    h[0] = f2bf(a.x); h[1] = f2bf(a.y); h[2] = f2bf(a.z); h[3] = f2bf(a.w);
    h[4] = f2bf(b.x); h[5] = f2bf(b.y); h[6] = f2bf(b.z); h[7] = f2bf(b.w);
    reinterpret_cast<us8*>(Xb)[i] = h;
  }
}

// ---------------- prepass 2: W nf4 packed -> bf16 (dequant once) ----------------
__global__ __launch_bounds__(256) void dequant_w(const int* __restrict__ Wp,
                                                 const float* __restrict__ Amax,
                                                 unsigned short* __restrict__ Wb, int n4) {
  __shared__ float lutS[16];
  if (threadIdx.x < 16) {
    const float lut[16] = {-1.0f, -0.6961928009986877f, -0.5250730514526367f,
        -0.39491719007492065f, -0.28444138169288635f, -0.18477343022823334f,
        -0.08820830285549164f, 0.0f, 0.07107656449079514f, 0.14263366162776947f,
        0.22430233657360077f, 0.3203405737876892f, 0.4407068192958832f,
        0.5905631184577942f, 0.796090841293335f, 1.0f};
    lutS[threadIdx.x] = lut[threadIdx.x];
  }
  __syncthreads();
  for (int i = blockIdx.x * blockDim.x + threadIdx.x; i < n4;
       i += gridDim.x * blockDim.x) {
    const int j = i * 4;              // first int32 index (4 int32 = 8 weights)
    const int row = j >> 11;          // / (IN_F/2)
    const int coli = j & 2047;
    const float am = Amax[row * (IN_F / 64) + (coli >> 5)];  // 4 int32 never cross a 64-w block
    const int4 pk = reinterpret_cast<const int4*>(Wp)[i];
    us8 h; int c;
    c = pk.x & 255; h[0] = f2bf(lutS[c & 15] * am); h[1] = f2bf(lutS[c >> 4] * am);
    c = pk.y & 255; h[2] = f2bf(lutS[c & 15] * am); h[3] = f2bf(lutS[c >> 4] * am);
    c = pk.z & 255; h[4] = f2bf(lutS[c & 15] * am); h[5] = f2bf(lutS[c >> 4] * am);
    c = pk.w & 255; h[6] = f2bf(lutS[c & 15] * am); h[7] = f2bf(lutS[c >> 4] * am);
    reinterpret_cast<us8*>(Wb)[i] = h;
  }
}

// ---------------- main GEMM: m97 structure (global_load_lds, 128^2, BK=64) ----------------
__global__ __launch_bounds__(256, 4) void gemm_bt(
    const unsigned short* __restrict__ A,   // (M, K) bf16
    const unsigned short* __restrict__ B,   // (N, K) bf16  (B^T layout)
    const float* __restrict__ Bias, float* __restrict__ Out, int M) {
  __shared__ unsigned short As[BM * BK];   // 16 KiB, linear [128][64]
  __shared__ unsigned short Bs[BN * BK];   // 16 KiB, linear

  const int t = threadIdx.x;
  const int l = t & 63;
  const int wid = t >> 6;

  // XCD-aware swizzle (grid = 5504, divisible by 8 -> simple form is bijective)
  const int ntile = OUT_F / BN;                 // 86
  const int nwg = (M / BM) * ntile;
  const int cpx = nwg >> 3;
  const int bid = (blockIdx.x & 7) * cpx + (blockIdx.x >> 3);
  const int m0 = (bid / ntile) * BM;
  const int n0 = (bid % ntile) * BN;

  const int wm = (wid >> 1) * 64;
  const int wn = (wid & 1) * 64;

  // staging: per wave-issue, 64 lanes x 16B = 1 KiB = 8 rows of 128B.
  // lane l -> row (l>>3), col-16B-chunk (l&7). 4 issues cover 128 rows/tile.
  const unsigned short* gA = A + (size_t)(m0 + wid * 8 + (l >> 3)) * IN_F + (l & 7) * 8;
  const unsigned short* gB = B + (size_t)(n0 + wid * 8 + (l >> 3)) * IN_F + (l & 7) * 8;

  f32x4 acc[4][4];
#pragma unroll
  for (int i = 0; i < 4; ++i)
#pragma unroll
    for (int j = 0; j < 4; ++j) acc[i][j] = {0.f, 0.f, 0.f, 0.f};

  for (int k0 = 0; k0 < IN_F; k0 += BK) {
#pragma unroll
    for (int p = 0; p < 4; ++p) {
      __builtin_amdgcn_global_load_lds(
          (const __attribute__((address_space(1))) void*)(gA + (size_t)p * 32 * IN_F + k0),
          (__attribute__((address_space(3))) void*)(As + (p * 32 + wid * 8) * 64),
          16, 0, 0);
      __builtin_amdgcn_global_load_lds(
          (const __attribute__((address_space(1))) void*)(gB + (size_t)p * 32 * IN_F + k0),
          (__attribute__((address_space(3))) void*)(Bs + (p * 32 + wid * 8) * 64),
          16, 0, 0);
    }
    __syncthreads();   // compiler emits vmcnt(0) drain before s_barrier

#pragma unroll
    for (int kk = 0; kk < BK; kk += 32) {
      bf16x8 af[4], bfv[4];
      const int kc = kk + ((l >> 4) << 3);
#pragma unroll
      for (int i = 0; i < 4; ++i)
        af[i] = *reinterpret_cast<const bf16x8*>(&As[(wm + i * 16 + (l & 15)) * 64 + kc]);
#pragma unroll
      for (int j = 0; j < 4; ++j)
        bfv[j] = *reinterpret_cast<const bf16x8*>(&Bs[(wn + j * 16 + (l & 15)) * 64 + kc]);
#pragma unroll
      for (int i = 0; i < 4; ++i)
#pragma unroll
        for (int j = 0; j < 4; ++j)
          acc[i][j] = __builtin_amdgcn_mfma_f32_16x16x32_bf16(af[i], bfv[j], acc[i][j], 0, 0, 0);
    }
    __syncthreads();
  }

  // epilogue: C = acc + bias   (C/D map: col = l&15, row = (l>>4)*4 + reg)
  const int crow0 = m0 + wm + ((l >> 4) << 2);
  const int ccol0 = n0 + wn + (l & 15);
#pragma unroll
  for (int j = 0; j < 4; ++j) {
    const float bv = Bias[ccol0 + j * 16];
#pragma unroll
    for (int i = 0; i < 4; ++i)
#pragma unroll
      for (int rg = 0; rg < 4; ++rg)
        Out[(size_t)(crow0 + i * 16 + rg) * OUT_F + ccol0 + j * 16] = acc[i][j][rg] + bv;
  }
}

// ---------------- fallback: round-1 fused kernel (if ws too small) ----------------
__global__ __launch_bounds__(256, 2) void nf4_gemm_fused(
    const float* __restrict__ X, const int* __restrict__ Wp,
    const float* __restrict__ Amax, const float* __restrict__ Bias,
    float* __restrict__ Out, int M) {
  __shared__ unsigned short As[BM * BK];
  __shared__ unsigned short Bs[BN * BK];
  __shared__ float lutS[16];

  const int t = threadIdx.x;
  const int l = t & 63;
  const int wid = t >> 6;

  if (t < 16) {
    const float lut[16] = {-1.0f, -0.6961928009986877f, -0.5250730514526367f,
        -0.39491719007492065f, -0.28444138169288635f, -0.18477343022823334f,
        -0.08820830285549164f, 0.0f, 0.07107656449079514f, 0.14263366162776947f,
        0.22430233657360077f, 0.3203405737876892f, 0.4407068192958832f,
        0.5905631184577942f, 0.796090841293335f, 1.0f};
    lutS[t] = lut[t];
  }

  const int ntile = OUT_F / BN;
  const int m0 = (blockIdx.x / ntile) * BM;
  const int n0 = (blockIdx.x % ntile) * BN;

  const int ar = t >> 4;
  const int ac4 = t & 15;
  const int br = t >> 3;
  const int bg = t & 7;
  const int wm = (wid >> 1) * 64;
  const int wn = (wid & 1) * 64;

  f32x4 acc[4][4];
#pragma unroll
  for (int i = 0; i < 4; ++i)
#pragma unroll
    for (int j = 0; j < 4; ++j) acc[i][j] = {0.f, 0.f, 0.f, 0.f};

  __syncthreads();

  for (int k0 = 0; k0 < IN_F; k0 += BK) {
#pragma unroll
    for (int p = 0; p < 8; ++p) {
      const int r = p * 16 + ar;
      const float4 v = *reinterpret_cast<const float4*>(
          X + (size_t)(m0 + r) * IN_F + k0 + ac4 * 4);
      us4 h;
      h[0] = f2bf(v.x); h[1] = f2bf(v.y); h[2] = f2bf(v.z); h[3] = f2bf(v.w);
      const int byte = r * 128 + ((ac4 * 8) ^ ((r & 7) << 4));
      *reinterpret_cast<us4*>(reinterpret_cast<char*>(As) + byte) = h;
    }
#pragma unroll
    for (int p = 0; p < 4; ++p) {
      const int r = p * 32 + br;
      const float amv = Amax[(size_t)(n0 + r) * (IN_F / 64) + (k0 >> 6)];
      const int4 pk = *reinterpret_cast<const int4*>(
          Wp + (size_t)(n0 + r) * (IN_F / 2) + (k0 >> 1) + bg * 4);
      us8 h;
      {
        int c;
        c = pk.x & 255; h[0] = f2bf(lutS[c & 15] * amv); h[1] = f2bf(lutS[c >> 4] * amv);
        c = pk.y & 255; h[2] = f2bf(lutS[c & 15] * amv); h[3] = f2bf(lutS[c >> 4] * amv);
        c = pk.z & 255; h[4] = f2bf(lutS[c & 15] * amv); h[5] = f2bf(lutS[c >> 4] * amv);
        c = pk.w & 255; h[6] = f2bf(lutS[c & 15] * amv); h[7] = f2bf(lutS[c >> 4] * amv);
      }
      const int byte = r * 128 + ((bg * 16) ^ ((r & 7) << 4));
      *reinterpret_cast<us8*>(reinterpret_cast<char*>(Bs) + byte) = h;
    }
    __syncthreads();

#pragma unroll
    for (int kk = 0; kk < BK; kk += 32) {
      bf16x8 af[4], bfv[4];
      const int kb = (kk + ((l >> 4) << 3)) * 2;
#pragma unroll
      for (int i = 0; i < 4; ++i) {
        const int row = wm + i * 16 + (l & 15);
        af[i] = *reinterpret_cast<const bf16x8*>(
            reinterpret_cast<const char*>(As) + row * 128 + (kb ^ ((row & 7) << 4)));
      }
#pragma unroll
      for (int j = 0; j < 4; ++j) {
        const int row = wn + j * 16 + (l & 15);
        bfv[j] = *reinterpret_cast<const bf16x8*>(
            reinterpret_cast<const char*>(Bs) + row * 128 + (kb ^ ((row & 7) << 4)));
      }
#pragma unroll
      for (int i = 0; i < 4; ++i)
#pragma unroll
        for (int j = 0; j < 4; ++j)
          acc[i][j] = __builtin_amdgcn_mfma_f32_16x16x32_bf16(af[i], bfv[j], acc[i][j], 0, 0, 0);
    }
    __syncthreads();
  }

  const int crow0 = m0 + wm + ((l >> 4) << 2);
  const int ccol0 = n0 + wn + (l & 15);
#pragma unroll
  for (int j = 0; j < 4; ++j) {
    const float bv = Bias[ccol0 + j * 16];
#pragma unroll
    for (int i = 0; i < 4; ++i)
#pragma unroll
      for (int rg = 0; rg < 4; ++rg)
        Out[(size_t)(crow0 + i * 16 + rg) * OUT_F + ccol0 + j * 16] = acc[i][j][rg] + bv;
  }
}

extern "C" void kernel_launch(void* const* d_in, const int* in_sizes, int n_in,
                              void* d_out, int out_size, void* d_ws, size_t ws_size,
                              hipStream_t stream) {
  const float* X = (const float*)d_in[0];
  const int* Wp = (const int*)d_in[1];
  const float* Amax = (const float*)d_in[2];
  const float* Bias = (const float*)d_in[3];
  float* Out = (float*)d_out;

  const int M = in_sizes[0] / IN_F;                       // 8192
  const size_t needX = (size_t)M * IN_F * 2;              // 67 MB
  const size_t needW = (size_t)OUT_F * IN_F * 2;          // 90 MB
  const int grid = (M / BM) * (OUT_F / BN);               // 5504

  if (ws_size >= needX + needW && (grid & 7) == 0) {
    unsigned short* Xb = (unsigned short*)d_ws;
    unsigned short* Wb = Xb + (size_t)M * IN_F;
    cvt_x<<<2048, 256, 0, stream>>>(X, Xb, M * (IN_F / 8));
    dequant_w<<<2048, 256, 0, stream>>>(Wp, Amax, Wb, OUT_F * (IN_F / 8));
    gemm_bt<<<grid, 256, 0, stream>>>(Xb, Wb, Bias, Out, M);
  } else {
    nf4_gemm_fused<<<grid, 256, 0, stream>>>(X, Wp, Amax, Bias, Out, M);
  }
}